// Round 5
// baseline (385.353 us; speedup 1.0000x reference)
//
#include <hip/hip_runtime.h>

// LSTMCell with attention, MI355X gfx950.
// Round 9: counted lgkmcnt. R4-R8 all pinned at MfmaUtil 33-35%: the per-phase
// full lgkmcnt(0) drain (12 lumpy reads -> ~400cyc CU LDS drain) sits serially
// in front of each 620cyc MFMA cluster. Fix: order reads first-use-first and
// wait with counted lgkmcnt(N) so the drain tail overlaps the first 8 MFMA.
// (m201's template notes exactly this for 12-read phases.) Everything else
// identical to R8: R4C8 swizzle, attS global scratch, LDS-coalesced epilogue.

typedef __attribute__((ext_vector_type(8))) __bf16 bf16x8;
typedef __attribute__((ext_vector_type(8))) unsigned short ushort8;
typedef __attribute__((ext_vector_type(4))) float f32x4;

#define AS1 __attribute__((address_space(1)))
#define AS3 __attribute__((address_space(3)))

__device__ __forceinline__ void gld16(const unsigned short* g, unsigned short* l) {
    __builtin_amdgcn_global_load_lds((const AS1 void*)g, (AS3 void*)l, 16, 0, 0);
}

__device__ __forceinline__ unsigned short f2bf(float f) {
    unsigned int u = __builtin_bit_cast(unsigned int, f);
    u += 0x7fffu + ((u >> 16) & 1u);   // RNE
    return (unsigned short)(u >> 16);
}

__device__ __forceinline__ float bf2f(unsigned short u) {
    unsigned int x = ((unsigned int)u) << 16;
    return __builtin_bit_cast(float, x);
}

__device__ __forceinline__ float sigmoidf_(float x) { return 1.f / (1.f + __expf(-x)); }
__device__ __forceinline__ float tanhf_(float x) {
    float e = __expf(-2.f * fabsf(x));
    float t = (1.f - e) / (1.f + e);
    return x >= 0.f ? t : -t;
}

__device__ __forceinline__ bf16x8 ldfrag(const unsigned short* p) {
    return __builtin_bit_cast(bf16x8, *(const ushort8*)p);
}

#define BARRIER __builtin_amdgcn_s_barrier()
#define LGKM_(n) asm volatile("s_waitcnt lgkmcnt(" #n ")" ::: "memory")
#define LGKM(n)  LGKM_(n)
#define FENCE    asm volatile("" ::: "memory")   // pins memory-op emission order
#define VMW_(n) asm volatile("s_waitcnt vmcnt(" #n ")" ::: "memory")
#define VMW(n)  VMW_(n)
#define PRIO1   __builtin_amdgcn_s_setprio(1)
#define PRIO0   __builtin_amdgcn_s_setprio(0)
#define MFMA16(a, b, c) __builtin_amdgcn_mfma_f32_16x16x32_bf16(a, b, c, 0, 0, 0)

// ---------------- fused cast/pack + bias kernel (BW-bound, ~33us) ----------------
__global__ void cast_all_k(const float* __restrict__ input, const float* __restrict__ hx,
                           const float* __restrict__ att,   const float* __restrict__ w_ih,
                           const float* __restrict__ w_hh,  const float* __restrict__ w_att,
                           const float* __restrict__ b_ih,  const float* __restrict__ b_hh,
                           unsigned short* __restrict__ XH, unsigned short* __restrict__ ATTb,
                           unsigned short* __restrict__ W4, unsigned short* __restrict__ WA,
                           float* __restrict__ bias4)
{
    int gid = blockIdx.x * blockDim.x + threadIdx.x;
    if (gid < 4096) bias4[gid] = b_ih[gid] + b_hh[gid];
    const int total = 4456448;  // total float8 units
    for (int i = gid; i < total; i += gridDim.x * blockDim.x) {
        const float* src; unsigned short* dst; int ld, off, rel;
        if (i < 1048576)      { src = input; dst = XH;   ld = 2048; off = 0;    rel = i; }
        else if (i < 2097152) { src = hx;    dst = XH;   ld = 2048; off = 1024; rel = i - 1048576; }
        else if (i < 3145728) { src = att;   dst = ATTb; ld = 1024; off = 0;    rel = i - 2097152; }
        else if (i < 3670016) { src = w_ih;  dst = W4;   ld = 2048; off = 0;    rel = i - 3145728; }
        else if (i < 4194304) { src = w_hh;  dst = W4;   ld = 2048; off = 1024; rel = i - 3670016; }
        else                  { src = w_att; dst = WA;   ld = 1024; off = 0;    rel = i - 4194304; }
        int e = rel * 8;
        int r = e >> 10, c = e & 1023;   // all sources have 1024 fp32 cols
        const float4 v0 = *(const float4*)(src + e);
        const float4 v1 = *(const float4*)(src + e + 4);
        ushort8 p;
        p[0] = f2bf(v0.x); p[1] = f2bf(v0.y); p[2] = f2bf(v0.z); p[3] = f2bf(v0.w);
        p[4] = f2bf(v1.x); p[5] = f2bf(v1.y); p[6] = f2bf(v1.z); p[7] = f2bf(v1.w);
        *(ushort8*)(dst + r * ld + off + c) = p;
    }
}

// ---------------- fused GEMM + full LSTM epilogue ----------------
__global__ __launch_bounds__(512, 2) void fused_gemm_k(
    const unsigned short* __restrict__ XH, const unsigned short* __restrict__ W4,
    const unsigned short* __restrict__ ATTb, const unsigned short* __restrict__ WA,
    const float* __restrict__ bias4, const float* __restrict__ bias_att,
    const float* __restrict__ cx, unsigned short* __restrict__ attS,
    float* __restrict__ out)
{
    __shared__ unsigned short As[2][16384];   // 2 x 32KB
    __shared__ unsigned short Bs[2][16384];   // 2 x 32KB

    const int tid  = threadIdx.x;
    const int wave = tid >> 6, lane = tid & 63;
    const int l15 = lane & 15, quad = lane >> 4;
    const int wr = wave >> 2, wn = wave & 3;

    // R4C8 swizzle: XCD = orig&7 owns row panels xcd*4..xcd*4+3 across all 16
    // col panels. Concurrent 32 blocks/XCD = 4 row panels x 8 col panels.
    const int orig  = blockIdx.x;
    const int xcd   = orig & 7, local = orig >> 3;
    const int row0  = (xcd * 4 + (local & 3)) * 256;   // 32 row panels
    const int n0    = (local >> 2) * 64;               // 16 col panels

    // ---- staging geometry: thread t stages LDS chunk (tid + p*512) of each half
    const int rl = tid >> 3;                         // 0..63
    const int c8 = (tid & 7) ^ (rl & 7);             // source k-chunk (swizzled)
    unsigned aG = (unsigned)(row0 + rl) * 2048u + (unsigned)c8 * 8u;
    unsigned bG = (unsigned)(((rl >> 4) & 3) * 1024 + n0 + (rl & 15)) * 2048u + (unsigned)c8 * 8u;
    unsigned aA = (unsigned)(row0 + rl) * 1024u + (unsigned)c8 * 8u;
    unsigned bA = (unsigned)(((rl >> 4) & 1) * 1024 + n0 + ((rl >> 5) & 1) * 16 + (rl & 15)) * 1024u
                  + (unsigned)c8 * 8u;

    auto stageA_att = [&](int buf) {   // 4 loads: 256x64 A tile
#pragma unroll
        for (int h = 0; h < 2; ++h)
#pragma unroll
            for (int p = 0; p < 2; ++p)
                gld16(ATTb + aA + (unsigned)(h * 131072 + p * 65536),
                      &As[buf][h * 8192 + (tid + p * 512) * 8]);
        aA += 64;
    };
    auto stageB_att = [&](int buf) {   // 2 loads: 128x64 B tile
#pragma unroll
        for (int h = 0; h < 2; ++h)
            gld16(WA + bA + (unsigned)(h * 32768), &Bs[buf][(h * 512 + tid) * 8]);
        bA += 64;
    };
    auto stageA_g = [&](int buf) {     // 4 loads: 256x64 A tile
#pragma unroll
        for (int h = 0; h < 2; ++h)
#pragma unroll
            for (int p = 0; p < 2; ++p)
                gld16(XH + aG + (unsigned)(h * 262144 + p * 131072),
                      &As[buf][h * 8192 + (tid + p * 512) * 8]);
        aG += 64;
    };
    auto stageB_g = [&](int buf) {     // 4 loads: 256x64 B tile
#pragma unroll
        for (int h = 0; h < 2; ++h)
#pragma unroll
            for (int p = 0; p < 2; ++p)
                gld16(W4 + bG + (unsigned)(h * 65536 + p * 32768),
                      &Bs[buf][h * 8192 + (tid + p * 512) * 8]);
        bG += 64;
    };

    // fragment read constants (lane-local)
    const int swz0 = (quad ^ (l15 & 7)) * 8;
    const int swz1 = ((4 + quad) ^ (l15 & 7)) * 8;
    const int aro  = (wr * 128 + l15) * 64;
    const int brG  = (wn * 64 + l15) * 64;
    const int brA  = (wn * 32 + l15) * 64;

    const f32x4 z = {0.f, 0.f, 0.f, 0.f};
    const int col = n0 + wn * 16 + l15;

    // ================= phase A: att GEMM, K=1024 (8 pairs of BK=64 tiles) =========
    {
        f32x4 acc2[8][2];
#pragma unroll
        for (int i = 0; i < 8; ++i) { acc2[i][0] = z; acc2[i][1] = z; }

        // reads ordered first-use-first: aS0-3 + bS (6), then aS4-7 (4).
        auto att_slice = [&](int buf, int sw) {
            bf16x8 aS[8], bS[2];
#pragma unroll
            for (int i = 0; i < 4; ++i) aS[i] = ldfrag(&As[buf][aro + i * 1024 + sw]);
#pragma unroll
            for (int j = 0; j < 2; ++j) bS[j] = ldfrag(&Bs[buf][brA + j * 1024 + sw]);
            FENCE;
#pragma unroll
            for (int i = 0; i < 4; ++i) aS[4 + i] = ldfrag(&As[buf][aro + (4 + i) * 1024 + sw]);
            BARRIER; LGKM(4);
            PRIO1;
#pragma unroll
            for (int i = 0; i < 4; ++i)
#pragma unroll
                for (int j = 0; j < 2; ++j)
                    acc2[i][j] = MFMA16(aS[i], bS[j], acc2[i][j]);
            LGKM(0);
#pragma unroll
            for (int i = 0; i < 4; ++i)
#pragma unroll
                for (int j = 0; j < 2; ++j)
                    acc2[4 + i][j] = MFMA16(aS[4 + i], bS[j], acc2[4 + i][j]);
            PRIO0;
            BARRIER;
        };

        stageA_att(0); stageB_att(0);            // tile0 -> buf0
        for (int g = 0; g < 8; ++g) {
            // stage odd tile (2g+1) -> buf1 (quiescent since prev pair's last barrier)
            stageA_att(1); stageB_att(1);
            VMW(6); BARRIER;                     // even tile landed everywhere
            att_slice(0, swz0);
            att_slice(0, swz1);                  // buf0 fully read at its barrier
            // stage next even tile (2g+2) -> buf0
            if (g < 7) { stageA_att(0); stageB_att(0); VMW(6); }
            else       { VMW(0); }
            BARRIER;                             // odd tile landed everywhere
            att_slice(1, swz0);
            att_slice(1, swz1);                  // buf1 quiescent for next g
        }

        // collapse att accumulators -> attS (global bf16 scratch).
        const float ba0 = bias_att[col], ba1 = bias_att[1024 + col];
#pragma unroll
        for (int i = 0; i < 8; ++i) {
            const int lr = wr * 128 + i * 16 + quad * 4;
#pragma unroll
            for (int r = 0; r < 4; ++r) {
                float v = sigmoidf_(acc2[i][0][r] + ba0) * tanhf_(acc2[i][1][r] + ba1);
                attS[(unsigned)(row0 + lr + r) * 1024u + (unsigned)col] = f2bf(v);
            }
        }
    }

    // ================= phase B: gates GEMM, K=2048 (32 tiles of BK=64) =============
    f32x4 acc[8][4];
#pragma unroll
    for (int i = 0; i < 8; ++i)
#pragma unroll
        for (int j = 0; j < 4; ++j) acc[i][j] = z;

    // m201 quadrant order with counted lgkm waits:
    // P1 rf0-3 x cf0-1 (reads 6+6, lgkm 6/0), P2 rf0-3 x cf2-3 (2+2, lgkm 2/0),
    // P3 rf4-7 x cf2-3 (4+4, stageB, lgkm 4/0), P4 rf4-7 x cf0-1 (0, stageA).
    auto gates_group = [&](int buf, bool iss) {
        bf16x8 aF0[4], aF1[4], aH0[4], aH1[4], bL0[2], bL1[2], bH0[2], bH1[2];
        // P1: s0 operands first, then s1
#pragma unroll
        for (int i = 0; i < 4; ++i) aF0[i] = ldfrag(&As[buf][aro + i * 1024 + swz0]);
#pragma unroll
        for (int j = 0; j < 2; ++j) bL0[j] = ldfrag(&Bs[buf][brG + j * 1024 + swz0]);
        FENCE;
#pragma unroll
        for (int i = 0; i < 4; ++i) aF1[i] = ldfrag(&As[buf][aro + i * 1024 + swz1]);
#pragma unroll
        for (int j = 0; j < 2; ++j) bL1[j] = ldfrag(&Bs[buf][brG + j * 1024 + swz1]);
        BARRIER; LGKM(6);
        PRIO1;
#pragma unroll
        for (int i = 0; i < 4; ++i)
#pragma unroll
            for (int j = 0; j < 2; ++j)
                acc[i][j] = MFMA16(aF0[i], bL0[j], acc[i][j]);
        LGKM(0);
#pragma unroll
        for (int i = 0; i < 4; ++i)
#pragma unroll
            for (int j = 0; j < 2; ++j)
                acc[i][j] = MFMA16(aF1[i], bL1[j], acc[i][j]);
        PRIO0;
        BARRIER;
        // P2: bHi (s0 first)
#pragma unroll
        for (int j = 0; j < 2; ++j) bH0[j] = ldfrag(&Bs[buf][brG + (2 + j) * 1024 + swz0]);
        FENCE;
#pragma unroll
        for (int j = 0; j < 2; ++j) bH1[j] = ldfrag(&Bs[buf][brG + (2 + j) * 1024 + swz1]);
        BARRIER; LGKM(2);
        PRIO1;
#pragma unroll
        for (int i = 0; i < 4; ++i)
#pragma unroll
            for (int j = 0; j < 2; ++j)
                acc[i][2 + j] = MFMA16(aF0[i], bH0[j], acc[i][2 + j]);
        LGKM(0);
#pragma unroll
        for (int i = 0; i < 4; ++i)
#pragma unroll
            for (int j = 0; j < 2; ++j)
                acc[i][2 + j] = MFMA16(aF1[i], bH1[j], acc[i][2 + j]);
        PRIO0;
        BARRIER;
        // P3: aHi (s0 first); stageB(t+2) (B region fully read after P2)
#pragma unroll
        for (int i = 0; i < 4; ++i) aH0[i] = ldfrag(&As[buf][aro + (4 + i) * 1024 + swz0]);
        FENCE;
#pragma unroll
        for (int i = 0; i < 4; ++i) aH1[i] = ldfrag(&As[buf][aro + (4 + i) * 1024 + swz1]);
        if (iss) stageB_g(buf);
        BARRIER; LGKM(4);
        PRIO1;
#pragma unroll
        for (int i = 0; i < 4; ++i)
#pragma unroll
            for (int j = 0; j < 2; ++j)
                acc[4 + i][2 + j] = MFMA16(aH0[i], bH0[j], acc[4 + i][2 + j]);
        LGKM(0);
#pragma unroll
        for (int i = 0; i < 4; ++i)
#pragma unroll
            for (int j = 0; j < 2; ++j)
                acc[4 + i][2 + j] = MFMA16(aH1[i], bH1[j], acc[4 + i][2 + j]);
        PRIO0;
        BARRIER;
        // P4: stageA(t+2) (A region fully read after P3); pure MFMA, bLo reused
        if (iss) stageA_g(buf);
        PRIO1;
#pragma unroll
        for (int i = 0; i < 4; ++i)
#pragma unroll
            for (int j = 0; j < 2; ++j) {
                acc[4 + i][j] = MFMA16(aH0[i], bL0[j], acc[4 + i][j]);
                acc[4 + i][j] = MFMA16(aH1[i], bL1[j], acc[4 + i][j]);
            }
        PRIO0;
    };

    stageA_g(0); stageB_g(0); stageA_g(1); stageB_g(1);   // tiles 0,1
    VMW(8); BARRIER;                                      // tile0 landed; tile1 in flight
#pragma unroll 2
    for (int t = 0; t < 30; ++t) {
        gates_group(t & 1, true);
        VMW(8); BARRIER;                                  // tile t+1 landed; t+2 in flight
    }
    gates_group(0, false); VMW(0); BARRIER;               // drain tile31
    gates_group(1, false);
    BARRIER;                                              // all LDS reads done before reuse

    // ---- epilogue: LSTM cell, coalesced via LDS ----
    // LDS reuse: sF (As, 64KB) holds fg then cy; sC (Bs, 64KB) holds cyP then og.
    float* sF = (float*)(&As[0][0]);
    float* sC = (float*)(&Bs[0][0]);
    const float bi  = bias4[col];
    const float bff = bias4[1024 + col];
    const float bg  = bias4[2048 + col];
    const float bo  = bias4[3072 + col];
    const int lcol  = wn * 16 + l15;
    const int CYOFF = 8192 * 1024;

    // step1: per-thread layout -> LDS (fg, cyP); col XOR'd by row bit2 (2-way banks)
#pragma unroll
    for (int i = 0; i < 8; ++i)
#pragma unroll
        for (int r = 0; r < 4; ++r) {
            const int lr = wr * 128 + i * 16 + quad * 4 + r;
            const int pc = lcol ^ (((lr >> 2) & 1) << 4);
            const float attv = bf2f(attS[(unsigned)(row0 + lr) * 1024u + (unsigned)col]);
            sF[lr * 64 + pc] = sigmoidf_(acc[i][1][r] + bff);
            sC[lr * 64 + pc] = sigmoidf_(acc[i][0][r] + bi) * tanhf_(acc[i][2][r] + bg)
                               + attv;
        }
    BARRIER;

    // step2: coalesced cy = fg*cx + cyP; write cy back into sF
    const int rr = tid >> 4;              // 0..31
    const int cc = (tid & 15) * 4;        // 0..60
#pragma unroll
    for (int p = 0; p < 8; ++p) {
        const int row = p * 32 + rr;
        const int pcc = cc ^ (((row >> 2) & 1) << 4);
        f32x4 fg4 = *(f32x4*)&sF[row * 64 + pcc];
        f32x4 cp4 = *(f32x4*)&sC[row * 64 + pcc];
        const float4 cx4 = *(const float4*)&cx[(row0 + row) * 1024 + n0 + cc];
        f32x4 cy4;
        cy4[0] = fg4[0] * cx4.x + cp4[0];
        cy4[1] = fg4[1] * cx4.y + cp4[1];
        cy4[2] = fg4[2] * cx4.z + cp4[2];
        cy4[3] = fg4[3] * cx4.w + cp4[3];
        *(f32x4*)&out[CYOFF + (row0 + row) * 1024 + n0 + cc] = cy4;
        *(f32x4*)&sF[row * 64 + pcc] = cy4;
    }
    BARRIER;

    // step3: per-thread og -> sC (cyP slots dead)
#pragma unroll
    for (int i = 0; i < 8; ++i)
#pragma unroll
        for (int r = 0; r < 4; ++r) {
            const int lr = wr * 128 + i * 16 + quad * 4 + r;
            const int pc = lcol ^ (((lr >> 2) & 1) << 4);
            sC[lr * 64 + pc] = sigmoidf_(acc[i][3][r] + bo);
        }
    BARRIER;

    // step4: coalesced hy = og * tanh(cy)
#pragma unroll
    for (int p = 0; p < 8; ++p) {
        const int row = p * 32 + rr;
        const int pcc = cc ^ (((row >> 2) & 1) << 4);
        f32x4 og4 = *(f32x4*)&sC[row * 64 + pcc];
        f32x4 cy4 = *(f32x4*)&sF[row * 64 + pcc];
        f32x4 hy4;
        hy4[0] = og4[0] * tanhf_(cy4[0]);
        hy4[1] = og4[1] * tanhf_(cy4[1]);
        hy4[2] = og4[2] * tanhf_(cy4[2]);
        hy4[3] = og4[3] * tanhf_(cy4[3]);
        *(f32x4*)&out[(row0 + row) * 1024 + n0 + cc] = hy4;
    }
}

// ---------------- launch ----------------
extern "C" void kernel_launch(void* const* d_in, const int* in_sizes, int n_in,
                              void* d_out, int out_size, void* d_ws, size_t ws_size,
                              hipStream_t stream) {
    const float* input = (const float*)d_in[0];
    const float* hx    = (const float*)d_in[1];
    const float* cx    = (const float*)d_in[2];
    const float* att   = (const float*)d_in[3];
    const float* w_ih  = (const float*)d_in[4];
    const float* w_hh  = (const float*)d_in[5];
    const float* b_ih  = (const float*)d_in[6];
    const float* b_hh  = (const float*)d_in[7];
    const float* w_att = (const float*)d_in[8];
    const float* b_att = (const float*)d_in[9];
    float* out = (float*)d_out;

    char* ws = (char*)d_ws;
    unsigned short* XH   = (unsigned short*)(ws);                    // 8192x2048 bf16 (32MB)
    unsigned short* ATTb = (unsigned short*)(ws + 33554432);         // 8192x1024 bf16 (16MB)
    unsigned short* W4   = (unsigned short*)(ws + 50331648);         // 4096x2048 bf16 (16MB)
    unsigned short* WA   = (unsigned short*)(ws + 67108864);         // 2048x1024 bf16 (4MB)
    float* bias4         = (float*)(ws + 71303168);                  // 4096 f32 (16KB)
    unsigned short* attS = (unsigned short*)(ws + 71319552);         // 8192x1024 bf16 (16MB)

    cast_all_k<<<8704, 256, 0, stream>>>(input, hx, att, w_ih, w_hh, w_att,
                                         b_ih, b_hh, XH, ATTb, W4, WA, bias4);
    fused_gemm_k<<<512, 512, 0, stream>>>(XH, W4, ATTb, WA, bias4, b_att, cx, attS, out);
}

// Round 6
// 381.318 us; speedup vs baseline: 1.0106x; 1.0106x over previous
//
#include <hip/hip_runtime.h>

// LSTMCell with attention, MI355X gfx950.
// Round 10: the hidden 175us. dur_us - fused_gemm_k ~= 175us constant across
// R0-R9: cast_all_k is VALU-bound (8 manual bit-twiddle RNE casts/unit ~55
// VALU ops -> ~240K cyc/SIMD ~= 115-170us), not the 34us BW-bound kernel it
// was assumed to be. Fix: v_cvt_pk_bf16_f32 (1 VALU per 2 elems, HW RNE,
// inline asm per T12 recipe), 1x16-float unit per thread (no loop), region
// branch block-uniform. fused_gemm_k byte-identical to R9 for attribution.

typedef __attribute__((ext_vector_type(8))) __bf16 bf16x8;
typedef __attribute__((ext_vector_type(8))) unsigned short ushort8;
typedef __attribute__((ext_vector_type(4))) float f32x4;
typedef __attribute__((ext_vector_type(4))) unsigned int u32x4;

#define AS1 __attribute__((address_space(1)))
#define AS3 __attribute__((address_space(3)))

__device__ __forceinline__ void gld16(const unsigned short* g, unsigned short* l) {
    __builtin_amdgcn_global_load_lds((const AS1 void*)g, (AS3 void*)l, 16, 0, 0);
}

__device__ __forceinline__ unsigned short f2bf(float f) {
    unsigned int u = __builtin_bit_cast(unsigned int, f);
    u += 0x7fffu + ((u >> 16) & 1u);   // RNE
    return (unsigned short)(u >> 16);
}

// HW packed convert: dst[15:0]=bf16(lo), dst[31:16]=bf16(hi). RNE.
__device__ __forceinline__ unsigned int cvtpk(float lo, float hi) {
    unsigned int r;
    asm("v_cvt_pk_bf16_f32 %0, %1, %2" : "=v"(r) : "v"(lo), "v"(hi));
    return r;
}

__device__ __forceinline__ float bf2f(unsigned short u) {
    unsigned int x = ((unsigned int)u) << 16;
    return __builtin_bit_cast(float, x);
}

__device__ __forceinline__ float sigmoidf_(float x) { return 1.f / (1.f + __expf(-x)); }
__device__ __forceinline__ float tanhf_(float x) {
    float e = __expf(-2.f * fabsf(x));
    float t = (1.f - e) / (1.f + e);
    return x >= 0.f ? t : -t;
}

__device__ __forceinline__ bf16x8 ldfrag(const unsigned short* p) {
    return __builtin_bit_cast(bf16x8, *(const ushort8*)p);
}

#define BARRIER __builtin_amdgcn_s_barrier()
#define LGKM_(n) asm volatile("s_waitcnt lgkmcnt(" #n ")" ::: "memory")
#define LGKM(n)  LGKM_(n)
#define FENCE    asm volatile("" ::: "memory")   // pins memory-op emission order
#define VMW_(n) asm volatile("s_waitcnt vmcnt(" #n ")" ::: "memory")
#define VMW(n)  VMW_(n)
#define PRIO1   __builtin_amdgcn_s_setprio(1)
#define PRIO0   __builtin_amdgcn_s_setprio(0)
#define MFMA16(a, b, c) __builtin_amdgcn_mfma_f32_16x16x32_bf16(a, b, c, 0, 0, 0)

// ---------------- fused cast/pack + bias kernel (now BW-bound) ----------------
// One 16-float unit per thread; grid 8704x256 = 2228224 units exactly.
// Region boundaries (in units): 524288 | 1048576 | 1572864 | 1835008 | 2097152,
// all divisible by 256 -> branch is block-uniform (scalar).
__global__ __launch_bounds__(256) void cast_all_k(
    const float* __restrict__ input, const float* __restrict__ hx,
    const float* __restrict__ att,   const float* __restrict__ w_ih,
    const float* __restrict__ w_hh,  const float* __restrict__ w_att,
    const float* __restrict__ b_ih,  const float* __restrict__ b_hh,
    unsigned short* __restrict__ XH, unsigned short* __restrict__ ATTb,
    unsigned short* __restrict__ W4, unsigned short* __restrict__ WA,
    float* __restrict__ bias4)
{
    const int gid = blockIdx.x * blockDim.x + threadIdx.x;
    if (gid < 4096) bias4[gid] = b_ih[gid] + b_hh[gid];

    const float* src; unsigned short* dst; int ld, off, rel;
    if      (gid <  524288) { src = input; dst = XH;   ld = 2048; off = 0;    rel = gid; }
    else if (gid < 1048576) { src = hx;    dst = XH;   ld = 2048; off = 1024; rel = gid -  524288; }
    else if (gid < 1572864) { src = att;   dst = ATTb; ld = 1024; off = 0;    rel = gid - 1048576; }
    else if (gid < 1835008) { src = w_ih;  dst = W4;   ld = 2048; off = 0;    rel = gid - 1572864; }
    else if (gid < 2097152) { src = w_hh;  dst = W4;   ld = 2048; off = 1024; rel = gid - 1835008; }
    else                    { src = w_att; dst = WA;   ld = 1024; off = 0;    rel = gid - 2097152; }

    const int e = rel * 16;            // 16 fp32 per thread, fully inside one row
    const int r = e >> 10, c = e & 1023;   // all sources have 1024 fp32 cols
    const float4 v0 = *(const float4*)(src + e);
    const float4 v1 = *(const float4*)(src + e + 4);
    const float4 v2 = *(const float4*)(src + e + 8);
    const float4 v3 = *(const float4*)(src + e + 12);
    u32x4 q0, q1;
    q0[0] = cvtpk(v0.x, v0.y); q0[1] = cvtpk(v0.z, v0.w);
    q0[2] = cvtpk(v1.x, v1.y); q0[3] = cvtpk(v1.z, v1.w);
    q1[0] = cvtpk(v2.x, v2.y); q1[1] = cvtpk(v2.z, v2.w);
    q1[2] = cvtpk(v3.x, v3.y); q1[3] = cvtpk(v3.z, v3.w);
    unsigned short* o = dst + r * ld + off + c;
    *(u32x4*)(o)     = q0;
    *(u32x4*)(o + 8) = q1;
}

// ---------------- fused GEMM + full LSTM epilogue (identical to R9) -------------
__global__ __launch_bounds__(512, 2) void fused_gemm_k(
    const unsigned short* __restrict__ XH, const unsigned short* __restrict__ W4,
    const unsigned short* __restrict__ ATTb, const unsigned short* __restrict__ WA,
    const float* __restrict__ bias4, const float* __restrict__ bias_att,
    const float* __restrict__ cx, unsigned short* __restrict__ attS,
    float* __restrict__ out)
{
    __shared__ unsigned short As[2][16384];   // 2 x 32KB
    __shared__ unsigned short Bs[2][16384];   // 2 x 32KB

    const int tid  = threadIdx.x;
    const int wave = tid >> 6, lane = tid & 63;
    const int l15 = lane & 15, quad = lane >> 4;
    const int wr = wave >> 2, wn = wave & 3;

    // R4C8 swizzle: XCD = orig&7 owns row panels xcd*4..xcd*4+3 across all 16
    // col panels. Concurrent 32 blocks/XCD = 4 row panels x 8 col panels.
    const int orig  = blockIdx.x;
    const int xcd   = orig & 7, local = orig >> 3;
    const int row0  = (xcd * 4 + (local & 3)) * 256;   // 32 row panels
    const int n0    = (local >> 2) * 64;               // 16 col panels

    // ---- staging geometry: thread t stages LDS chunk (tid + p*512) of each half
    const int rl = tid >> 3;                         // 0..63
    const int c8 = (tid & 7) ^ (rl & 7);             // source k-chunk (swizzled)
    unsigned aG = (unsigned)(row0 + rl) * 2048u + (unsigned)c8 * 8u;
    unsigned bG = (unsigned)(((rl >> 4) & 3) * 1024 + n0 + (rl & 15)) * 2048u + (unsigned)c8 * 8u;
    unsigned aA = (unsigned)(row0 + rl) * 1024u + (unsigned)c8 * 8u;
    unsigned bA = (unsigned)(((rl >> 4) & 1) * 1024 + n0 + ((rl >> 5) & 1) * 16 + (rl & 15)) * 1024u
                  + (unsigned)c8 * 8u;

    auto stageA_att = [&](int buf) {   // 4 loads: 256x64 A tile
#pragma unroll
        for (int h = 0; h < 2; ++h)
#pragma unroll
            for (int p = 0; p < 2; ++p)
                gld16(ATTb + aA + (unsigned)(h * 131072 + p * 65536),
                      &As[buf][h * 8192 + (tid + p * 512) * 8]);
        aA += 64;
    };
    auto stageB_att = [&](int buf) {   // 2 loads: 128x64 B tile
#pragma unroll
        for (int h = 0; h < 2; ++h)
            gld16(WA + bA + (unsigned)(h * 32768), &Bs[buf][(h * 512 + tid) * 8]);
        bA += 64;
    };
    auto stageA_g = [&](int buf) {     // 4 loads: 256x64 A tile
#pragma unroll
        for (int h = 0; h < 2; ++h)
#pragma unroll
            for (int p = 0; p < 2; ++p)
                gld16(XH + aG + (unsigned)(h * 262144 + p * 131072),
                      &As[buf][h * 8192 + (tid + p * 512) * 8]);
        aG += 64;
    };
    auto stageB_g = [&](int buf) {     // 4 loads: 256x64 B tile
#pragma unroll
        for (int h = 0; h < 2; ++h)
#pragma unroll
            for (int p = 0; p < 2; ++p)
                gld16(W4 + bG + (unsigned)(h * 65536 + p * 32768),
                      &Bs[buf][h * 8192 + (tid + p * 512) * 8]);
        bG += 64;
    };

    // fragment read constants (lane-local)
    const int swz0 = (quad ^ (l15 & 7)) * 8;
    const int swz1 = ((4 + quad) ^ (l15 & 7)) * 8;
    const int aro  = (wr * 128 + l15) * 64;
    const int brG  = (wn * 64 + l15) * 64;
    const int brA  = (wn * 32 + l15) * 64;

    const f32x4 z = {0.f, 0.f, 0.f, 0.f};
    const int col = n0 + wn * 16 + l15;

    // ================= phase A: att GEMM, K=1024 (8 pairs of BK=64 tiles) =========
    {
        f32x4 acc2[8][2];
#pragma unroll
        for (int i = 0; i < 8; ++i) { acc2[i][0] = z; acc2[i][1] = z; }

        // reads ordered first-use-first: aS0-3 + bS (6), then aS4-7 (4).
        auto att_slice = [&](int buf, int sw) {
            bf16x8 aS[8], bS[2];
#pragma unroll
            for (int i = 0; i < 4; ++i) aS[i] = ldfrag(&As[buf][aro + i * 1024 + sw]);
#pragma unroll
            for (int j = 0; j < 2; ++j) bS[j] = ldfrag(&Bs[buf][brA + j * 1024 + sw]);
            FENCE;
#pragma unroll
            for (int i = 0; i < 4; ++i) aS[4 + i] = ldfrag(&As[buf][aro + (4 + i) * 1024 + sw]);
            BARRIER; LGKM(4);
            PRIO1;
#pragma unroll
            for (int i = 0; i < 4; ++i)
#pragma unroll
                for (int j = 0; j < 2; ++j)
                    acc2[i][j] = MFMA16(aS[i], bS[j], acc2[i][j]);
            LGKM(0);
#pragma unroll
            for (int i = 0; i < 4; ++i)
#pragma unroll
                for (int j = 0; j < 2; ++j)
                    acc2[4 + i][j] = MFMA16(aS[4 + i], bS[j], acc2[4 + i][j]);
            PRIO0;
            BARRIER;
        };

        stageA_att(0); stageB_att(0);            // tile0 -> buf0
        for (int g = 0; g < 8; ++g) {
            // stage odd tile (2g+1) -> buf1 (quiescent since prev pair's last barrier)
            stageA_att(1); stageB_att(1);
            VMW(6); BARRIER;                     // even tile landed everywhere
            att_slice(0, swz0);
            att_slice(0, swz1);                  // buf0 fully read at its barrier
            // stage next even tile (2g+2) -> buf0
            if (g < 7) { stageA_att(0); stageB_att(0); VMW(6); }
            else       { VMW(0); }
            BARRIER;                             // odd tile landed everywhere
            att_slice(1, swz0);
            att_slice(1, swz1);                  // buf1 quiescent for next g
        }

        // collapse att accumulators -> attS (global bf16 scratch).
        const float ba0 = bias_att[col], ba1 = bias_att[1024 + col];
#pragma unroll
        for (int i = 0; i < 8; ++i) {
            const int lr = wr * 128 + i * 16 + quad * 4;
#pragma unroll
            for (int r = 0; r < 4; ++r) {
                float v = sigmoidf_(acc2[i][0][r] + ba0) * tanhf_(acc2[i][1][r] + ba1);
                attS[(unsigned)(row0 + lr + r) * 1024u + (unsigned)col] = f2bf(v);
            }
        }
    }

    // ================= phase B: gates GEMM, K=2048 (32 tiles of BK=64) =============
    f32x4 acc[8][4];
#pragma unroll
    for (int i = 0; i < 8; ++i)
#pragma unroll
        for (int j = 0; j < 4; ++j) acc[i][j] = z;

    // m201 quadrant order with counted lgkm waits:
    // P1 rf0-3 x cf0-1 (reads 6+6, lgkm 6/0), P2 rf0-3 x cf2-3 (2+2, lgkm 2/0),
    // P3 rf4-7 x cf2-3 (4+4, stageB, lgkm 4/0), P4 rf4-7 x cf0-1 (0, stageA).
    auto gates_group = [&](int buf, bool iss) {
        bf16x8 aF0[4], aF1[4], aH0[4], aH1[4], bL0[2], bL1[2], bH0[2], bH1[2];
        // P1: s0 operands first, then s1
#pragma unroll
        for (int i = 0; i < 4; ++i) aF0[i] = ldfrag(&As[buf][aro + i * 1024 + swz0]);
#pragma unroll
        for (int j = 0; j < 2; ++j) bL0[j] = ldfrag(&Bs[buf][brG + j * 1024 + swz0]);
        FENCE;
#pragma unroll
        for (int i = 0; i < 4; ++i) aF1[i] = ldfrag(&As[buf][aro + i * 1024 + swz1]);
#pragma unroll
        for (int j = 0; j < 2; ++j) bL1[j] = ldfrag(&Bs[buf][brG + j * 1024 + swz1]);
        BARRIER; LGKM(6);
        PRIO1;
#pragma unroll
        for (int i = 0; i < 4; ++i)
#pragma unroll
            for (int j = 0; j < 2; ++j)
                acc[i][j] = MFMA16(aF0[i], bL0[j], acc[i][j]);
        LGKM(0);
#pragma unroll
        for (int i = 0; i < 4; ++i)
#pragma unroll
            for (int j = 0; j < 2; ++j)
                acc[i][j] = MFMA16(aF1[i], bL1[j], acc[i][j]);
        PRIO0;
        BARRIER;
        // P2: bHi (s0 first)
#pragma unroll
        for (int j = 0; j < 2; ++j) bH0[j] = ldfrag(&Bs[buf][brG + (2 + j) * 1024 + swz0]);
        FENCE;
#pragma unroll
        for (int j = 0; j < 2; ++j) bH1[j] = ldfrag(&Bs[buf][brG + (2 + j) * 1024 + swz1]);
        BARRIER; LGKM(2);
        PRIO1;
#pragma unroll
        for (int i = 0; i < 4; ++i)
#pragma unroll
            for (int j = 0; j < 2; ++j)
                acc[i][2 + j] = MFMA16(aF0[i], bH0[j], acc[i][2 + j]);
        LGKM(0);
#pragma unroll
        for (int i = 0; i < 4; ++i)
#pragma unroll
            for (int j = 0; j < 2; ++j)
                acc[i][2 + j] = MFMA16(aF1[i], bH1[j], acc[i][2 + j]);
        PRIO0;
        BARRIER;
        // P3: aHi (s0 first); stageB(t+2) (B region fully read after P2)
#pragma unroll
        for (int i = 0; i < 4; ++i) aH0[i] = ldfrag(&As[buf][aro + (4 + i) * 1024 + swz0]);
        FENCE;
#pragma unroll
        for (int i = 0; i < 4; ++i) aH1[i] = ldfrag(&As[buf][aro + (4 + i) * 1024 + swz1]);
        if (iss) stageB_g(buf);
        BARRIER; LGKM(4);
        PRIO1;
#pragma unroll
        for (int i = 0; i < 4; ++i)
#pragma unroll
            for (int j = 0; j < 2; ++j)
                acc[4 + i][2 + j] = MFMA16(aH0[i], bH0[j], acc[4 + i][2 + j]);
        LGKM(0);
#pragma unroll
        for (int i = 0; i < 4; ++i)
#pragma unroll
            for (int j = 0; j < 2; ++j)
                acc[4 + i][2 + j] = MFMA16(aH1[i], bH1[j], acc[4 + i][2 + j]);
        PRIO0;
        BARRIER;
        // P4: stageA(t+2) (A region fully read after P3); pure MFMA, bLo reused
        if (iss) stageA_g(buf);
        PRIO1;
#pragma unroll
        for (int i = 0; i < 4; ++i)
#pragma unroll
            for (int j = 0; j < 2; ++j) {
                acc[4 + i][j] = MFMA16(aH0[i], bL0[j], acc[4 + i][j]);
                acc[4 + i][j] = MFMA16(aH1[i], bL1[j], acc[4 + i][j]);
            }
        PRIO0;
    };

    stageA_g(0); stageB_g(0); stageA_g(1); stageB_g(1);   // tiles 0,1
    VMW(8); BARRIER;                                      // tile0 landed; tile1 in flight
#pragma unroll 2
    for (int t = 0; t < 30; ++t) {
        gates_group(t & 1, true);
        VMW(8); BARRIER;                                  // tile t+1 landed; t+2 in flight
    }
    gates_group(0, false); VMW(0); BARRIER;               // drain tile31
    gates_group(1, false);
    BARRIER;                                              // all LDS reads done before reuse

    // ---- epilogue: LSTM cell, coalesced via LDS ----
    // LDS reuse: sF (As, 64KB) holds fg then cy; sC (Bs, 64KB) holds cyP then og.
    float* sF = (float*)(&As[0][0]);
    float* sC = (float*)(&Bs[0][0]);
    const float bi  = bias4[col];
    const float bff = bias4[1024 + col];
    const float bg  = bias4[2048 + col];
    const float bo  = bias4[3072 + col];
    const int lcol  = wn * 16 + l15;
    const int CYOFF = 8192 * 1024;

    // step1: per-thread layout -> LDS (fg, cyP); col XOR'd by row bit2 (2-way banks)
#pragma unroll
    for (int i = 0; i < 8; ++i)
#pragma unroll
        for (int r = 0; r < 4; ++r) {
            const int lr = wr * 128 + i * 16 + quad * 4 + r;
            const int pc = lcol ^ (((lr >> 2) & 1) << 4);
            const float attv = bf2f(attS[(unsigned)(row0 + lr) * 1024u + (unsigned)col]);
            sF[lr * 64 + pc] = sigmoidf_(acc[i][1][r] + bff);
            sC[lr * 64 + pc] = sigmoidf_(acc[i][0][r] + bi) * tanhf_(acc[i][2][r] + bg)
                               + attv;
        }
    BARRIER;

    // step2: coalesced cy = fg*cx + cyP; write cy back into sF
    const int rr = tid >> 4;              // 0..31
    const int cc = (tid & 15) * 4;        // 0..60
#pragma unroll
    for (int p = 0; p < 8; ++p) {
        const int row = p * 32 + rr;
        const int pcc = cc ^ (((row >> 2) & 1) << 4);
        f32x4 fg4 = *(f32x4*)&sF[row * 64 + pcc];
        f32x4 cp4 = *(f32x4*)&sC[row * 64 + pcc];
        const float4 cx4 = *(const float4*)&cx[(row0 + row) * 1024 + n0 + cc];
        f32x4 cy4;
        cy4[0] = fg4[0] * cx4.x + cp4[0];
        cy4[1] = fg4[1] * cx4.y + cp4[1];
        cy4[2] = fg4[2] * cx4.z + cp4[2];
        cy4[3] = fg4[3] * cx4.w + cp4[3];
        *(f32x4*)&out[CYOFF + (row0 + row) * 1024 + n0 + cc] = cy4;
        *(f32x4*)&sF[row * 64 + pcc] = cy4;
    }
    BARRIER;

    // step3: per-thread og -> sC (cyP slots dead)
#pragma unroll
    for (int i = 0; i < 8; ++i)
#pragma unroll
        for (int r = 0; r < 4; ++r) {
            const int lr = wr * 128 + i * 16 + quad * 4 + r;
            const int pc = lcol ^ (((lr >> 2) & 1) << 4);
            sC[lr * 64 + pc] = sigmoidf_(acc[i][3][r] + bo);
        }
    BARRIER;

    // step4: coalesced hy = og * tanh(cy)
#pragma unroll
    for (int p = 0; p < 8; ++p) {
        const int row = p * 32 + rr;
        const int pcc = cc ^ (((row >> 2) & 1) << 4);
        f32x4 og4 = *(f32x4*)&sC[row * 64 + pcc];
        f32x4 cy4 = *(f32x4*)&sF[row * 64 + pcc];
        f32x4 hy4;
        hy4[0] = og4[0] * tanhf_(cy4[0]);
        hy4[1] = og4[1] * tanhf_(cy4[1]);
        hy4[2] = og4[2] * tanhf_(cy4[2]);
        hy4[3] = og4[3] * tanhf_(cy4[3]);
        *(f32x4*)&out[(row0 + row) * 1024 + n0 + cc] = hy4;
    }
}

// ---------------- launch ----------------
extern "C" void kernel_launch(void* const* d_in, const int* in_sizes, int n_in,
                              void* d_out, int out_size, void* d_ws, size_t ws_size,
                              hipStream_t stream) {
    const float* input = (const float*)d_in[0];
    const float* hx    = (const float*)d_in[1];
    const float* cx    = (const float*)d_in[2];
    const float* att   = (const float*)d_in[3];
    const float* w_ih  = (const float*)d_in[4];
    const float* w_hh  = (const float*)d_in[5];
    const float* b_ih  = (const float*)d_in[6];
    const float* b_hh  = (const float*)d_in[7];
    const float* w_att = (const float*)d_in[8];
    const float* b_att = (const float*)d_in[9];
    float* out = (float*)d_out;

    char* ws = (char*)d_ws;
    unsigned short* XH   = (unsigned short*)(ws);                    // 8192x2048 bf16 (32MB)
    unsigned short* ATTb = (unsigned short*)(ws + 33554432);         // 8192x1024 bf16 (16MB)
    unsigned short* W4   = (unsigned short*)(ws + 50331648);         // 4096x2048 bf16 (16MB)
    unsigned short* WA   = (unsigned short*)(ws + 67108864);         // 2048x1024 bf16 (4MB)
    float* bias4         = (float*)(ws + 71303168);                  // 4096 f32 (16KB)
    unsigned short* attS = (unsigned short*)(ws + 71319552);         // 8192x1024 bf16 (16MB)

    cast_all_k<<<8704, 256, 0, stream>>>(input, hx, att, w_ih, w_hh, w_att,
                                         b_ih, b_hh, XH, ATTb, W4, WA, bias4);
    fused_gemm_k<<<512, 512, 0, stream>>>(XH, W4, ATTb, WA, bias4, b_att, cx, attS, out);
}